// Round 8
// baseline (112.712 us; speedup 1.0000x reference)
//
#include <hip/hip_runtime.h>
#include <math.h>

#define B   8
#define NA  33600
#define M   64
#define NC  80
#define KK  13
#define EPSF 1e-9f
#define PIF 3.14159265358979323846f

#define PCAP 1536          // per-(b,m) positive capacity (max in-circle ~1100)

// ---------------------------------------------------------------- helpers

__device__ __forceinline__ float circle_iou(float gx, float gy, float gr,
                                            float px, float py, float pr) {
    float dx = gx - px, dy = gy - py;
    float d  = sqrtf(dx * dx + dy * dy + 1e-12f);
    float r0sq = gr * gr, r1sq = pr * pr;
    float d1 = (r0sq - r1sq + d * d) / (2.0f * d);
    float d2 = d - d1;
    float t0 = fminf(fmaxf(d1 / fmaxf(gr, EPSF), -1.0f), 1.0f);
    float t1 = fminf(fmaxf(d2 / fmaxf(pr, EPSF), -1.0f), 1.0f);
    float a0 = r0sq * acosf(t0) - d1 * sqrtf(fmaxf(r0sq - d1 * d1, 0.0f));
    float a1 = r1sq * acosf(t1) - d2 * sqrtf(fmaxf(r1sq - d2 * d2, 0.0f));
    float lens = a0 + a1;
    float rmin = fminf(gr, pr);
    float contained = PIF * rmin * rmin;
    float inter = (d >= gr + pr) ? 0.0f
                : ((d <= fabsf(gr - pr)) ? contained : lens);
    float uni = PIF * r0sq + PIF * r1sq - inter;
    return (uni > 0.0f) ? inter / uni : 0.0f;
}

// masked overlap + align_metric for one (b, gt, anchor) — reference formula
__device__ __forceinline__ void ov_met(const float* __restrict__ pd_scores,
                                       const float* __restrict__ pd_circles,
                                       const float* __restrict__ anc,
                                       int b, int a,
                                       float gx, float gy, float gr, int gl, float gmask,
                                       float* ov_out, float* met_out) {
    float ax = anc[2 * a], ay = anc[2 * a + 1];
    float dx = ax - gx, dy = ay - gy;
    float dan = sqrtf(dx * dx + dy * dy);
    float ov = 0.0f, met = 0.0f;
    if (gmask > 0.0f && dan < gr) {
        int base = (b * NA + a) * 3;
        float px = pd_circles[base + 0];
        float py = pd_circles[base + 1];
        float pr = pd_circles[base + 2];
        float cdx = gx - px, cdy = gy - py;
        float dc = sqrtf(cdx * cdx + cdy * cdy + 1e-12f);
        float iou = (dc >= gr + pr) ? 0.0f : circle_iou(gx, gy, gr, px, py, pr);
        ov = iou * gmask;
        if (ov > 0.0f) {
            float sc = pd_scores[(size_t)(b * NA + a) * NC + gl] * gmask;
            float o2 = ov * ov;
            met = sc * (o2 * o2 * o2);          // score^1 * ov^6
        }
    }
    *ov_out = ov; *met_out = met;
}

// ---------------------------------------------------------------- K1: per-anchor dense build
// coalesced pd_circles stream; disjoint cut before the only random gather
// (pd_scores, ~3K total). Also zeroes fg_count/sel_m (ordered before K2 use).

__global__ __launch_bounds__(256)
void k_build(const float* __restrict__ pd_scores, const float* __restrict__ pd_circles,
             const float* __restrict__ anc, const int* __restrict__ gt_labels,
             const float* __restrict__ gt_circles, const float* __restrict__ mask_gt,
             int* __restrict__ plist_cnt, int* __restrict__ plist_a,
             float* __restrict__ plist_v,
             int* __restrict__ fg_count, int* __restrict__ sel_m) {
    int b = blockIdx.y;
    __shared__ float s_gx[M], s_gy[M], s_gr[M];
    __shared__ int   s_gl[M], s_act[M];
    if (threadIdx.x < M) {
        int gi = b * M + threadIdx.x;
        s_act[threadIdx.x] = mask_gt[gi] > 0.0f;
        s_gx[threadIdx.x] = gt_circles[gi * 3 + 0];
        s_gy[threadIdx.x] = gt_circles[gi * 3 + 1];
        s_gr[threadIdx.x] = gt_circles[gi * 3 + 2];
        int l = gt_labels[gi];
        s_gl[threadIdx.x] = l < 0 ? 0 : (l > NC - 1 ? NC - 1 : l);
    }
    __syncthreads();

    int a = blockIdx.x * 256 + threadIdx.x;
    if (a >= NA) return;
    int i = b * NA + a;
    fg_count[i] = 0;                 // consumed by K2/K3 (kernel-boundary ordered)
    sel_m[i] = 0x7fffffff;

    float2 ap = reinterpret_cast<const float2*>(anc)[a];
    float px = pd_circles[i * 3 + 0];   // dense coalesced stream
    float py = pd_circles[i * 3 + 1];
    float pr = pd_circles[i * 3 + 2];

    for (int m = 0; m < M; m++) {
        if (!s_act[m]) continue;                    // wave-uniform
        float gx = s_gx[m], gy = s_gy[m], gr = s_gr[m];
        float dxa = ap.x - gx, dya = ap.y - gy;
        if (!(sqrtf(dxa * dxa + dya * dya) < gr)) continue;   // anchor in gt?
        float cdx = gx - px, cdy = gy - py;
        float dc = sqrtf(cdx * cdx + cdy * cdy + 1e-12f);
        if (dc >= gr + pr) continue;                // disjoint -> iou 0 -> met 0
        float ov = circle_iou(gx, gy, gr, px, py, pr);        // gmask == 1 here
        if (!(ov > 0.0f)) continue;
        float sc = pd_scores[(size_t)i * NC + s_gl[m]];       // rare random gather
        float o2 = ov * ov;
        float met = sc * (o2 * o2 * o2);
        if (met > 0.0f) {
            int bm = b * M + m;
            int p = atomicAdd(&plist_cnt[bm], 1);   // ~6 per counter: uncontended
            if (p < PCAP) { plist_a[bm * PCAP + p] = a; plist_v[bm * PCAP + p] = met; }
        }
    }
}

// ---------------------------------------------------------------- K2: per-(b,m) top-13 + gather-free zero-fill + scatter
// one wave per (b,m); pure VALU/LDS (no random global gathers at all).

__global__ __launch_bounds__(64)
void k_select(const float* __restrict__ anc, const float* __restrict__ gt_circles,
              const float* __restrict__ mask_gt,
              const int* __restrict__ plist_cnt, const int* __restrict__ plist_a,
              const float* __restrict__ plist_v,
              int* __restrict__ fg_count, int* __restrict__ sel_m,
              int* __restrict__ pos_align_i, int* __restrict__ pos_ov_i) {
    int bm = blockIdx.x;
    int b  = bm / M;
    int m  = bm - b * M;
    int tid = threadIdx.x;

    __shared__ int   s_pa[PCAP];
    __shared__ float s_pv[PCAP];
    __shared__ int   s_win[KK];

    if (tid == 0) { pos_align_i[bm] = 0; pos_ov_i[bm] = 0; }  // consumed by K3

    float gmask = mask_gt[bm];
    if (!(gmask > 0.0f)) return;

    float gx = gt_circles[bm * 3 + 0];
    float gy = gt_circles[bm * 3 + 1];
    float gr = gt_circles[bm * 3 + 2];

    int pcnt = plist_cnt[bm]; if (pcnt > PCAP) pcnt = PCAP;
    for (int i = tid; i < pcnt; i += 64) {
        s_pa[i] = plist_a[bm * PCAP + i];
        s_pv[i] = plist_v[bm * PCAP + i];
    }
    __syncthreads();

    // 13 rounds of argmax (val desc, anchor asc) == lax.top_k order
    for (int k = 0; k < KK; k++) {
        float bv = 0.0f; int ba = 0x7fffffff; int bp = -1;
        for (int i = tid; i < pcnt; i += 64) {
            float v = s_pv[i];
            if (v > 0.0f) {
                int a = s_pa[i];
                if (v > bv || (v == bv && a < ba)) { bv = v; ba = a; bp = i; }
            }
        }
        for (int off = 32; off > 0; off >>= 1) {
            float v2 = __shfl_xor(bv, off);
            int   a2 = __shfl_xor(ba, off);
            int   p2 = __shfl_xor(bp, off);
            if (v2 > bv || (v2 == bv && a2 < ba)) { bv = v2; ba = a2; bp = p2; }
        }
        if (tid == 0) {
            if (bp >= 0) { s_win[k] = ba; s_pv[bp] = -1.0f; }
            else s_win[k] = -2;
        }
    }

    // zero-fill WITHOUT gathers: align_metric == 0  <=>  anchor not in positive
    // list, so top_k's zero tie-break = lowest indices absent from the list.
    int defmask = 0;
    for (int k = 0; k < KK; k++) if (s_win[k] == -2) defmask |= (1 << k);
    if (defmask) {
        int base = 0;
        while (defmask && base < NA) {
            int idx = base + tid;
            bool freez = (idx < NA);
            for (int i = 0; i < pcnt; i++)       // LDS broadcast scan, pcnt ~6
                freez = freez && (s_pa[i] != idx);
            unsigned long long msk = __ballot(freez);
            while (msk && defmask) {
                int bit = __ffsll((long long)msk) - 1; msk &= msk - 1;
                int k2  = __ffs(defmask) - 1;          defmask &= defmask - 1;
                if (tid == 0) s_win[k2] = base + bit;
            }
            base += 64;
        }
        while (defmask) {
            int k2 = __ffs(defmask) - 1; defmask &= defmask - 1;
            if (tid == 0) s_win[k2] = -1;
        }
    }

    // winners enter mask_pos only if anchor center inside the gt circle; scatter
    if (tid < KK) {
        int a = s_win[tid];
        if (a >= 0) {
            float ax = anc[2 * a], ay = anc[2 * a + 1];
            float dx = ax - gx, dy = ay - gy;
            if (sqrtf(dx * dx + dy * dy) < gr) {
                atomicAdd(&fg_count[b * NA + a], 1);
                atomicMin(&sel_m[b * NA + a], m);
            }
        }
    }
}

// ---------------------------------------------------------------- K3 fused: per-anchor resolve + pos maxima

__global__ void k_resolve_posmax(const float* __restrict__ pd_scores,
                                 const float* __restrict__ pd_circles, const float* __restrict__ anc,
                                 const int* __restrict__ gt_labels, const float* __restrict__ gt_circles,
                                 const float* __restrict__ mask_gt,
                                 const int* __restrict__ fg_count, const int* __restrict__ sel_m,
                                 int* __restrict__ assigned, float* __restrict__ am_val,
                                 int* __restrict__ pos_align_i, int* __restrict__ pos_ov_i,
                                 float* __restrict__ out_labels, float* __restrict__ out_circles,
                                 float* __restrict__ out_fg, float* __restrict__ out_gtidx) {
    int i = blockIdx.x * blockDim.x + threadIdx.x;
    if (i >= B * NA) return;
    int b = i / NA, a = i - b * NA;
    int c = fg_count[i];
    int g = 0, fg = 0;
    if (c == 1) { g = sel_m[i]; fg = 1; }
    else if (c > 1) {
        // jnp.argmax over masked overlaps, lowest index wins ties
        float ax = anc[2 * a], ay = anc[2 * a + 1];
        int pbase = i * 3;
        float px = pd_circles[pbase], py = pd_circles[pbase + 1], pr = pd_circles[pbase + 2];
        float best = -1.0f; int bmx = 0;
        for (int mm = 0; mm < M; mm++) {
            float gmask = mask_gt[b * M + mm];
            float gx = gt_circles[(b * M + mm) * 3 + 0];
            float gy = gt_circles[(b * M + mm) * 3 + 1];
            float grr = gt_circles[(b * M + mm) * 3 + 2];
            float dx = ax - gx, dy = ay - gy;
            float ov = 0.0f;
            if (gmask > 0.0f && sqrtf(dx * dx + dy * dy) < grr)
                ov = circle_iou(gx, gy, grr, px, py, pr) * gmask;
            if (ov > best) { best = ov; bmx = mm; }
        }
        g = bmx; fg = 1;
    }
    assigned[i] = fg ? g : -1;
    int lbl = gt_labels[b * M + g]; if (lbl < 0) lbl = 0;   // clip(.., 0, None)
    out_labels[i] = (float)lbl;
    out_circles[(size_t)i * 3 + 0] = gt_circles[(b * M + g) * 3 + 0];
    out_circles[(size_t)i * 3 + 1] = gt_circles[(b * M + g) * 3 + 1];
    out_circles[(size_t)i * 3 + 2] = gt_circles[(b * M + g) * 3 + 2];
    out_fg[i]    = fg ? 1.0f : 0.0f;
    out_gtidx[i] = (float)g;

    if (!fg) { am_val[i] = 0.0f; return; }
    float gmask = mask_gt[b * M + g];
    float gx = gt_circles[(b * M + g) * 3 + 0];
    float gy = gt_circles[(b * M + g) * 3 + 1];
    float grc = gt_circles[(b * M + g) * 3 + 2];
    int gl2 = gt_labels[b * M + g];
    gl2 = gl2 < 0 ? 0 : (gl2 > NC - 1 ? NC - 1 : gl2);
    float ov, met;
    ov_met(pd_scores, pd_circles, anc, b, a, gx, gy, grc, gl2, gmask, &ov, &met);
    am_val[i] = met;
    atomicMax(&pos_align_i[b * M + g], __float_as_int(met));  // values >= 0
    atomicMax(&pos_ov_i[b * M + g],    __float_as_int(ov));
}

// ---------------------------------------------------------------- K4 target_scores (86 MB write)

__global__ void k_scores(const int* __restrict__ assigned, const float* __restrict__ am_val,
                         const int* __restrict__ pos_align_i, const int* __restrict__ pos_ov_i,
                         const int* __restrict__ gt_labels,
                         float* __restrict__ out_scores) {
    int q = blockIdx.x * blockDim.x + threadIdx.x;      // one float4 per thread
    if (q >= (B * NA * NC) / 4) return;
    int idx = q * 4;
    int row = idx / NC;
    int c0  = idx - row * NC;
    float4 v = make_float4(0.f, 0.f, 0.f, 0.f);
    int g = assigned[row];
    if (g >= 0) {
        int b = row / NA;
        float pa = __int_as_float(pos_align_i[b * M + g]);
        float po = __int_as_float(pos_ov_i[b * M + g]);
        float norm = am_val[row] * po / (pa + EPSF);
        int lbl = gt_labels[b * M + g]; if (lbl < 0) lbl = 0;
        int off = lbl - c0;
        if (off >= 0 && off < 4) ((float*)&v)[off] = norm;
    }
    reinterpret_cast<float4*>(out_scores)[q] = v;
}

// ---------------------------------------------------------------- launch

extern "C" void kernel_launch(void* const* d_in, const int* in_sizes, int n_in,
                              void* d_out, int out_size, void* d_ws, size_t ws_size,
                              hipStream_t stream) {
    const float* pd_scores  = (const float*)d_in[0];   // (B, NA, NC)
    const float* pd_circles = (const float*)d_in[1];   // (B, NA, 3)
    const float* anc        = (const float*)d_in[2];   // (NA, 2)
    const int*   gt_labels  = (const int*)  d_in[3];   // (B, M, 1)
    const float* gt_circles = (const float*)d_in[4];   // (B, M, 3)
    const float* mask_gt    = (const float*)d_in[5];   // (B, M, 1)

    // workspace layout
    char* w = (char*)d_ws;
    int*   plist_cnt   = (int*)w;   w += (size_t)B * M * sizeof(int);
    int*   plist_a     = (int*)w;   w += (size_t)B * M * PCAP * sizeof(int);
    float* plist_v     = (float*)w; w += (size_t)B * M * PCAP * sizeof(float);
    int*   fg_count    = (int*)w;   w += (size_t)B * NA * sizeof(int);
    int*   sel_m       = (int*)w;   w += (size_t)B * NA * sizeof(int);
    int*   assigned    = (int*)w;   w += (size_t)B * NA * sizeof(int);
    float* am_val      = (float*)w; w += (size_t)B * NA * sizeof(float);
    int*   pos_align_i = (int*)w;   w += (size_t)B * M * sizeof(int);
    int*   pos_ov_i    = (int*)w;   w += (size_t)B * M * sizeof(int);

    // output layout (concat in return order, float32)
    float* out        = (float*)d_out;
    float* out_labels = out;                              // B*NA
    float* out_circ   = out_labels + (size_t)B * NA;      // B*NA*3
    float* out_scores = out_circ + (size_t)B * NA * 3;    // B*NA*NC
    float* out_fg     = out_scores + (size_t)B * NA * NC; // B*NA
    float* out_gtidx  = out_fg + (size_t)B * NA;          // B*NA

    const int T = 256;
    int gBA = (B * NA + T - 1) / T;

    hipMemsetAsync(plist_cnt, 0, (size_t)B * M * sizeof(int), stream);

    dim3 gb((NA + 255) / 256, B);
    k_build<<<gb, 256, 0, stream>>>(pd_scores, pd_circles, anc, gt_labels,
                                    gt_circles, mask_gt, plist_cnt, plist_a, plist_v,
                                    fg_count, sel_m);

    k_select<<<B * M, 64, 0, stream>>>(anc, gt_circles, mask_gt,
                                       plist_cnt, plist_a, plist_v,
                                       fg_count, sel_m, pos_align_i, pos_ov_i);

    k_resolve_posmax<<<gBA, T, 0, stream>>>(pd_scores, pd_circles, anc, gt_labels,
                                            gt_circles, mask_gt, fg_count, sel_m,
                                            assigned, am_val, pos_align_i, pos_ov_i,
                                            out_labels, out_circ, out_fg, out_gtidx);

    int nq = (B * NA * NC) / 4;
    k_scores<<<(nq + T - 1) / T, T, 0, stream>>>(assigned, am_val, pos_align_i, pos_ov_i,
                                                 gt_labels, out_scores);
}